// Round 23
// baseline (46.876 us; speedup 1.0000x reference)
//
#include <hip/hip_runtime.h>

// Log-sparse attention, B=4 H=8 L=4096 E=64 fp32, win_len<=32.
// Quad-per-query, fp16 LDS, fdot2. Round-23: SINGLE-PASS FUSED softmax with
// fixed offset C=8 (softmax is shift-invariant; C replaces the running max,
// exact up to fp rounding -- scores |s|<~8 so exp(s-C) in [e-16, 1], safe in
// f32). Eliminates: score arrays, max pass, quad_bcast redistribution, and
// the entire second key-walk. One fused loop: K+V rows -> dot -> p -> den,
// acc (f32, mix-FMA). Pow2 keys done fully PRE-barrier from global (score+PV
// overlap the staging stores). R16 two-pass structure (43.3us) is the
// fallback if this nulls.

constexpr int L     = 4096;
constexpr int E     = 64;
constexpr int QPB   = 64;            // queries per block (256 thr / 4)
constexpr int WMAX  = 32;
constexpr int WROWS = QPB + WMAX;    // 96 staged rows
constexpr int RS    = 160;           // LDS row stride bytes
constexpr int CS    = 40;            // chunk stride bytes (32 data + 8 pad)
constexpr int VOFF  = WROWS * RS;    // V region offset (15360)
constexpr int TPB   = L / QPB;       // 64 tiles per (b,h)
constexpr int NP2   = 6;             // pow2 dists 64..2048

typedef _Float16 h2  __attribute__((ext_vector_type(2)));   // arithmetic type
typedef __fp16   h2c __attribute__((ext_vector_type(2)));   // builtin interop

__device__ __forceinline__ h2 pkrtz(float a, float b) {
    h2c r = __builtin_amdgcn_cvt_pkrtz(a, b);
    return __builtin_bit_cast(h2, r);
}

#if defined(__has_builtin)
#if __has_builtin(__builtin_amdgcn_fdot2)
#define HAVE_FDOT2 1
#endif
#endif

__device__ __forceinline__ float fdot2h(h2 a, h2 b, float c) {
#ifdef HAVE_FDOT2
    return __builtin_amdgcn_fdot2(__builtin_bit_cast(h2c, a),
                                  __builtin_bit_cast(h2c, b), c, false);
#else
    return fmaf((float)a.x, (float)b.x, fmaf((float)a.y, (float)b.y, c));
#endif
}

__device__ __forceinline__ h2 as_h2(unsigned u) {
    return __builtin_bit_cast(h2, u);
}
__device__ __forceinline__ unsigned as_u32(h2 h) {
    return __builtin_bit_cast(unsigned, h);
}

// ---- DPP quad_perm cross-lane (VALU pipe; 4-lane groups) ----
template<int CTRL>
__device__ __forceinline__ float dppf(float x) {
    return __int_as_float(__builtin_amdgcn_update_dpp(
        0, __float_as_int(x), CTRL, 0xF, 0xF, true));
}
__device__ __forceinline__ float quad_sum(float x) {
    x += dppf<0xB1>(x);   // quad_perm [1,0,3,2]
    x += dppf<0x4E>(x);   // quad_perm [2,3,0,1]
    return x;
}

__global__ __launch_bounds__(256) void logsparse_attn(
    const float* __restrict__ q,
    const float* __restrict__ k,
    const float* __restrict__ v,
    float* __restrict__ out,
    const int* __restrict__ win_ptr)
{
    __shared__ alignas(16) unsigned char buf[2 * WROWS * RS];   // 30720 B

    const int bid = blockIdx.x, nb = gridDim.x;
    int swz = bid;
    if ((nb & 7) == 0) {                       // bijective XCD swizzle
        const int cpx = nb >> 3;
        swz = (bid & 7) * cpx + (bid >> 3);
    }
    const int bh  = swz / TPB;
    const int t   = (swz % TPB) * QPB;
    const int tid = threadIdx.x;
    const int qid = tid >> 2;                  // query within block (0..63)
    const int s   = tid & 3;                   // lane within quad = chunk id
    const int i   = t + qid;                   // this quad's query position
    const int ce  = s * 16;                    // chunk base element
    int win = *win_ptr; win = min(win, WMAX);

    const size_t base = (size_t)bh * (L * E);
    const float* kb = k + base;
    const float* vb = v + base;

    const float C = 8.0f;                      // fixed softmax offset

    // ---- this lane's q chunk as 8 x h2, scale folded (1/8) ----
    h2 qh[8];
    {
        const float* qp = q + base + (size_t)i * E + ce;
        #pragma unroll
        for (int u = 0; u < 4; ++u) {
            float4 f = *(const float4*)(qp + u * 4);
            qh[u*2+0] = pkrtz(f.x * 0.125f, f.y * 0.125f);
            qh[u*2+1] = pkrtz(f.z * 0.125f, f.w * 0.125f);
        }
    }

    // ---- stage K AND V window rows [t-32, t+64) as fp16, chunked layout ----
    #pragma unroll
    for (int it = 0; it < 6; ++it) {
        int idx = tid + it * 256;
        int r = idx >> 4, w = idx & 15;
        int cc = w >> 2, p = w & 3;
        int j = max(t - WMAX + r, 0);
        float4 fk = *(const float4*)(kb + (size_t)j * E + w * 4);
        float4 fv = *(const float4*)(vb + (size_t)j * E + w * 4);
        uint2 pk; pk.x = as_u32(pkrtz(fk.x, fk.y)); pk.y = as_u32(pkrtz(fk.z, fk.w));
        uint2 pv; pv.x = as_u32(pkrtz(fv.x, fv.y)); pv.y = as_u32(pkrtz(fv.z, fv.w));
        *(uint2*)(buf + r * RS + cc * CS + p * 8) = pk;
        *(uint2*)(buf + VOFF + r * RS + cc * CS + p * 8) = pv;
    }

    float den = 0.f;
    float acc[16];
    #pragma unroll
    for (int e = 0; e < 16; ++e) acc[e] = 0.f;

    // ---- pow2 keys COMPLETE pre-barrier: score + PV direct from global ----
    #pragma unroll
    for (int dd = 0; dd < NP2; ++dd) {
        const int d = 64 << dd;
        if (t + QPB - 1 >= d) {                // block-uniform skip
            const int j = max(i - d, 0);
            const float* kr = kb + (size_t)j * E + ce;
            float a0 = 0.f, a1 = 0.f;
            #pragma unroll
            for (int u = 0; u < 4; ++u) {
                float4 f = *(const float4*)(kr + u * 4);
                a0 = fdot2h(pkrtz(f.x, f.y), qh[u*2+0], a0);
                a1 = fdot2h(pkrtz(f.z, f.w), qh[u*2+1], a1);
            }
            float sv = quad_sum(a0 + a1);
            const float p2 = (i >= d) ? __expf(sv - C) : 0.f;
            den += p2;
            const float* vr = vb + (size_t)j * E + ce;
            #pragma unroll
            for (int u = 0; u < 4; ++u) {
                float4 f = *(const float4*)(vr + u * 4);
                acc[u*4+0] = fmaf(f.x, p2, acc[u*4+0]);
                acc[u*4+1] = fmaf(f.y, p2, acc[u*4+1]);
                acc[u*4+2] = fmaf(f.z, p2, acc[u*4+2]);
                acc[u*4+3] = fmaf(f.w, p2, acc[u*4+3]);
            }
        }
    }

    __syncthreads();                 // the ONLY barrier in the kernel

    // ---- fused window loop: K dot -> p -> den, acc (one walk, two chains) ----
    #pragma unroll
    for (int o = 0; o <= WMAX; ++o) {
        const unsigned char* kp = buf + (qid + WMAX - o) * RS + s * CS;
        const unsigned char* vp = buf + VOFF + (qid + WMAX - o) * RS + s * CS;
        uint2 u0 = *(const uint2*)(kp);
        uint2 u1 = *(const uint2*)(kp + 8);
        uint2 u2 = *(const uint2*)(kp + 16);
        uint2 u3 = *(const uint2*)(kp + 24);
        uint2 w0 = *(const uint2*)(vp);
        uint2 w1 = *(const uint2*)(vp + 8);
        uint2 w2 = *(const uint2*)(vp + 16);
        uint2 w3 = *(const uint2*)(vp + 24);
        float a0 = 0.f, a1 = 0.f;
        a0 = fdot2h(as_h2(u0.x), qh[0], a0); a1 = fdot2h(as_h2(u0.y), qh[1], a1);
        a0 = fdot2h(as_h2(u1.x), qh[2], a0); a1 = fdot2h(as_h2(u1.y), qh[3], a1);
        a0 = fdot2h(as_h2(u2.x), qh[4], a0); a1 = fdot2h(as_h2(u2.y), qh[5], a1);
        a0 = fdot2h(as_h2(u3.x), qh[6], a0); a1 = fdot2h(as_h2(u3.y), qh[7], a1);
        float sv = quad_sum(a0 + a1);
        const bool isp2  = (o > 0) && ((o & (o - 1)) == 0);
        const bool valid = ((o <= win) || isp2) && (o <= i);
        const float p = valid ? __expf(sv - C) : 0.f;
        den += p;
        h2 v0 = as_h2(w0.x), v1 = as_h2(w0.y), v2 = as_h2(w1.x), v3 = as_h2(w1.y);
        h2 v4 = as_h2(w2.x), v5 = as_h2(w2.y), v6 = as_h2(w3.x), v7 = as_h2(w3.y);
        acc[0]  = fmaf((float)v0.x, p, acc[0]);  acc[1]  = fmaf((float)v0.y, p, acc[1]);
        acc[2]  = fmaf((float)v1.x, p, acc[2]);  acc[3]  = fmaf((float)v1.y, p, acc[3]);
        acc[4]  = fmaf((float)v2.x, p, acc[4]);  acc[5]  = fmaf((float)v2.y, p, acc[5]);
        acc[6]  = fmaf((float)v3.x, p, acc[6]);  acc[7]  = fmaf((float)v3.y, p, acc[7]);
        acc[8]  = fmaf((float)v4.x, p, acc[8]);  acc[9]  = fmaf((float)v4.y, p, acc[9]);
        acc[10] = fmaf((float)v5.x, p, acc[10]); acc[11] = fmaf((float)v5.y, p, acc[11]);
        acc[12] = fmaf((float)v6.x, p, acc[12]); acc[13] = fmaf((float)v6.y, p, acc[13]);
        acc[14] = fmaf((float)v7.x, p, acc[14]); acc[15] = fmaf((float)v7.y, p, acc[15]);
    }

    // ---- normalize + write (den identical across the quad by construction) ----
    const float inv = 1.0f / den;
    float* op = out + base + (size_t)i * E + ce;
    #pragma unroll
    for (int u = 0; u < 4; ++u) {
        float4 o4;
        o4.x = acc[u*4+0] * inv; o4.y = acc[u*4+1] * inv;
        o4.z = acc[u*4+2] * inv; o4.w = acc[u*4+3] * inv;
        *(float4*)(op + u * 4) = o4;
    }
}

extern "C" void kernel_launch(void* const* d_in, const int* in_sizes, int n_in,
                              void* d_out, int out_size, void* d_ws, size_t ws_size,
                              hipStream_t stream) {
    const float* q = (const float*)d_in[0];
    const float* k = (const float*)d_in[1];
    const float* v = (const float*)d_in[2];
    const int* win = (const int*)d_in[3];
    float* out = (float*)d_out;

    const int n_rows = in_sizes[0] / E;        // B*H*L = 131072
    const int blocks = n_rows / QPB;           // 2048
    logsparse_attn<<<blocks, 256, 0, stream>>>(q, k, v, out, win);
}

// Round 24
// 43.463 us; speedup vs baseline: 1.0785x; 1.0785x over previous
//
#include <hip/hip_runtime.h>

// Log-sparse attention, B=4 H=8 L=4096 E=64 fp32, win_len<=32.
// FINAL (revert-to-best): Round-16 kernel verbatim -- session best 43.3us.
// Quad-per-query (4 lanes/query, 16 elems each); K+V staged upfront in LDS
// as fp16 (conflict-free 160/40B chunked layout); scores via v_dot2_f32_f16
// with 4-deep LDS register ring; pow2 scores pre-barrier from global
// (overlap staging); quad softmax via DPP quad_perm; PV via v_pk_fma_f16
// with the same ring; pow2 PV 2-deep global prefetch ring.
// Plateau evidence: R17-R23 (broadcast-row, LDS time-share, MFMA, launch
// bounds, mem fences, fused softmax) all >= 43.3us; no pipe >45% busy;
// binding constraint is dep-chain latency at the allocator's VGPR=48
// operating point, not a hardware roofline.

constexpr int L     = 4096;
constexpr int E     = 64;
constexpr int QPB   = 64;            // queries per block (256 thr / 4)
constexpr int WMAX  = 32;
constexpr int WROWS = QPB + WMAX;    // 96 staged rows
constexpr int RS    = 160;           // LDS row stride bytes
constexpr int CS    = 40;            // chunk stride bytes (32 data + 8 pad)
constexpr int VOFF  = WROWS * RS;    // V region offset (15360)
constexpr int TPB   = L / QPB;       // 64 tiles per (b,h)
constexpr int NP2   = 6;             // pow2 dists 64..2048

typedef _Float16 h2  __attribute__((ext_vector_type(2)));   // arithmetic type
typedef __fp16   h2c __attribute__((ext_vector_type(2)));   // builtin interop

__device__ __forceinline__ h2 pkrtz(float a, float b) {
    h2c r = __builtin_amdgcn_cvt_pkrtz(a, b);
    return __builtin_bit_cast(h2, r);
}

#if defined(__has_builtin)
#if __has_builtin(__builtin_amdgcn_fdot2)
#define HAVE_FDOT2 1
#endif
#endif

__device__ __forceinline__ float fdot2h(h2 a, h2 b, float c) {
#ifdef HAVE_FDOT2
    return __builtin_amdgcn_fdot2(__builtin_bit_cast(h2c, a),
                                  __builtin_bit_cast(h2c, b), c, false);
#else
    return fmaf((float)a.x, (float)b.x, fmaf((float)a.y, (float)b.y, c));
#endif
}

__device__ __forceinline__ h2 as_h2(unsigned u) {
    return __builtin_bit_cast(h2, u);
}
__device__ __forceinline__ unsigned as_u32(h2 h) {
    return __builtin_bit_cast(unsigned, h);
}

// ---- DPP quad_perm cross-lane (VALU pipe; 4-lane groups) ----
template<int CTRL>
__device__ __forceinline__ float dppf(float x) {
    return __int_as_float(__builtin_amdgcn_update_dpp(
        0, __float_as_int(x), CTRL, 0xF, 0xF, true));
}
__device__ __forceinline__ float quad_sum(float x) {
    x += dppf<0xB1>(x);   // quad_perm [1,0,3,2]
    x += dppf<0x4E>(x);   // quad_perm [2,3,0,1]
    return x;
}
__device__ __forceinline__ float quad_max(float x) {
    x = fmaxf(x, dppf<0xB1>(x));
    x = fmaxf(x, dppf<0x4E>(x));
    return x;
}
__device__ __forceinline__ float quad_bcast(float x, int r) {
    switch (r & 3) {
    case 0:  return dppf<0x00>(x);
    case 1:  return dppf<0x55>(x);
    case 2:  return dppf<0xAA>(x);
    default: return dppf<0xFF>(x);
    }
}

__global__ __launch_bounds__(256) void logsparse_attn(
    const float* __restrict__ q,
    const float* __restrict__ k,
    const float* __restrict__ v,
    float* __restrict__ out,
    const int* __restrict__ win_ptr)
{
    __shared__ alignas(16) unsigned char buf[2 * WROWS * RS];   // 30720 B

    const int bid = blockIdx.x, nb = gridDim.x;
    int swz = bid;
    if ((nb & 7) == 0) {                       // bijective XCD swizzle
        const int cpx = nb >> 3;
        swz = (bid & 7) * cpx + (bid >> 3);
    }
    const int bh  = swz / TPB;
    const int t   = (swz % TPB) * QPB;
    const int tid = threadIdx.x;
    const int qid = tid >> 2;                  // query within block (0..63)
    const int s   = tid & 3;                   // lane within quad = chunk id
    const int i   = t + qid;                   // this quad's query position
    const int ce  = s * 16;                    // chunk base element
    int win = *win_ptr; win = min(win, WMAX);

    const size_t base = (size_t)bh * (L * E);
    const float* kb = k + base;
    const float* vb = v + base;

    // ---- this lane's q chunk as 8 x h2, scale folded (1/8) ----
    h2 qh[8];
    {
        const float* qp = q + base + (size_t)i * E + ce;
        #pragma unroll
        for (int u = 0; u < 4; ++u) {
            float4 f = *(const float4*)(qp + u * 4);
            qh[u*2+0] = pkrtz(f.x * 0.125f, f.y * 0.125f);
            qh[u*2+1] = pkrtz(f.z * 0.125f, f.w * 0.125f);
        }
    }

    // ---- stage K AND V window rows [t-32, t+64) as fp16, chunked layout ----
    #pragma unroll
    for (int it = 0; it < 6; ++it) {
        int idx = tid + it * 256;
        int r = idx >> 4, w = idx & 15;
        int cc = w >> 2, p = w & 3;
        int j = max(t - WMAX + r, 0);
        float4 fk = *(const float4*)(kb + (size_t)j * E + w * 4);
        float4 fv = *(const float4*)(vb + (size_t)j * E + w * 4);
        uint2 pk; pk.x = as_u32(pkrtz(fk.x, fk.y)); pk.y = as_u32(pkrtz(fk.z, fk.w));
        uint2 pv; pv.x = as_u32(pkrtz(fv.x, fv.y)); pv.y = as_u32(pkrtz(fv.z, fv.w));
        *(uint2*)(buf + r * RS + cc * CS + p * 8) = pk;
        *(uint2*)(buf + VOFF + r * RS + cc * CS + p * 8) = pv;
    }

    // ---- pow2 scores BEFORE barrier: global K, overlaps staging stores ----
    float wp[2];
    wp[0] = wp[1] = -60000.f;
    #pragma unroll
    for (int dd = 0; dd < NP2; ++dd) {
        const int d = 64 << dd;
        if (t + QPB - 1 >= d) {                // block-uniform skip
            const int j = max(i - d, 0);
            const float* kr = kb + (size_t)j * E + ce;
            float a0 = 0.f, a1 = 0.f;
            #pragma unroll
            for (int u = 0; u < 4; ++u) {
                float4 f = *(const float4*)(kr + u * 4);
                a0 = fdot2h(pkrtz(f.x, f.y), qh[u*2+0], a0);
                a1 = fdot2h(pkrtz(f.z, f.w), qh[u*2+1], a1);
            }
            float sv = quad_sum(a0 + a1);
            sv = (i >= d) ? sv : -60000.f;
            if (s == ((WMAX + 1 + dd) & 3)) wp[dd < 4 ? 0 : 1] = sv;
        }
    }

    __syncthreads();                 // the ONLY barrier in the kernel

    // ---- window scores: 4-deep LDS register ring ----
    float ws[9];
    #pragma unroll
    for (int kk = 0; kk < 9; ++kk) ws[kk] = -60000.f;

    uint2 pf[4][4];
    #pragma unroll
    for (int o = 0; o < 4; ++o) {
        const unsigned char* rp = buf + (qid + WMAX - o) * RS + s * CS;
        pf[o][0] = *(const uint2*)(rp);
        pf[o][1] = *(const uint2*)(rp + 8);
        pf[o][2] = *(const uint2*)(rp + 16);
        pf[o][3] = *(const uint2*)(rp + 24);
    }
    #pragma unroll
    for (int o = 0; o <= WMAX; ++o) {
        float a0 = 0.f, a1 = 0.f;
        a0 = fdot2h(as_h2(pf[o & 3][0].x), qh[0], a0);
        a1 = fdot2h(as_h2(pf[o & 3][0].y), qh[1], a1);
        a0 = fdot2h(as_h2(pf[o & 3][1].x), qh[2], a0);
        a1 = fdot2h(as_h2(pf[o & 3][1].y), qh[3], a1);
        a0 = fdot2h(as_h2(pf[o & 3][2].x), qh[4], a0);
        a1 = fdot2h(as_h2(pf[o & 3][2].y), qh[5], a1);
        a0 = fdot2h(as_h2(pf[o & 3][3].x), qh[6], a0);
        a1 = fdot2h(as_h2(pf[o & 3][3].y), qh[7], a1);
        float sv = quad_sum(a0 + a1);
        const bool isp2  = (o > 0) && ((o & (o - 1)) == 0);
        const bool valid = ((o <= win) || isp2) && (o <= i);
        sv = valid ? sv : -60000.f;
        if (s == (o & 3)) ws[o >> 2] = sv;
        if (o + 4 <= WMAX) {                   // reload this slot with key o+4
            const unsigned char* rp = buf + (qid + WMAX - (o + 4)) * RS + s * CS;
            pf[o & 3][0] = *(const uint2*)(rp);
            pf[o & 3][1] = *(const uint2*)(rp + 8);
            pf[o & 3][2] = *(const uint2*)(rp + 16);
            pf[o & 3][3] = *(const uint2*)(rp + 24);
        }
    }

    // ---- softmax across the quad's distributed scores ----
    float ml = ws[0];
    #pragma unroll
    for (int kk = 1; kk < 9; ++kk) ml = fmaxf(ml, ws[kk]);
    ml = fmaxf(ml, fmaxf(wp[0], wp[1]));
    const float m = quad_max(ml);

    float ew[9], ep0, ep1, dl = 0.f;
    #pragma unroll
    for (int kk = 0; kk < 9; ++kk) { ew[kk] = __expf(ws[kk] - m); dl += ew[kk]; }
    ep0 = __expf(wp[0] - m); ep1 = __expf(wp[1] - m); dl += ep0 + ep1;
    const float inv = 1.0f / quad_sum(dl);
    #pragma unroll
    for (int kk = 0; kk < 9; ++kk) ew[kk] *= inv;
    ep0 *= inv; ep1 *= inv;

    // ---- pow2 PV prefetch (2-deep ring), issued before window PV ----
    float4 vpf[2][4];
    #pragma unroll
    for (int dd = 0; dd < 2; ++dd) {
        if (t + QPB - 1 >= (64 << dd)) {
            const float* vr = vb + (size_t)max(i - (64 << dd), 0) * E + ce;
            vpf[dd][0] = *(const float4*)(vr);
            vpf[dd][1] = *(const float4*)(vr + 4);
            vpf[dd][2] = *(const float4*)(vr + 8);
            vpf[dd][3] = *(const float4*)(vr + 12);
        }
    }

    // ---- window PV: 4-deep LDS register ring, packed fp16 accumulate ----
    h2 ah[8];
    #pragma unroll
    for (int j = 0; j < 8; ++j) ah[j] = h2{(_Float16)0.f, (_Float16)0.f};

    #pragma unroll
    for (int o = 0; o < 4; ++o) {
        const unsigned char* rp = buf + VOFF + (qid + WMAX - o) * RS + s * CS;
        pf[o][0] = *(const uint2*)(rp);
        pf[o][1] = *(const uint2*)(rp + 8);
        pf[o][2] = *(const uint2*)(rp + 16);
        pf[o][3] = *(const uint2*)(rp + 24);
    }
    #pragma unroll
    for (int o = 0; o <= WMAX; ++o) {
        const float pd = quad_bcast(ew[o >> 2], o & 3);   // 0 if masked
        const h2 pdh = pkrtz(pd, pd);
        ah[0] += as_h2(pf[o & 3][0].x) * pdh; ah[1] += as_h2(pf[o & 3][0].y) * pdh;
        ah[2] += as_h2(pf[o & 3][1].x) * pdh; ah[3] += as_h2(pf[o & 3][1].y) * pdh;
        ah[4] += as_h2(pf[o & 3][2].x) * pdh; ah[5] += as_h2(pf[o & 3][2].y) * pdh;
        ah[6] += as_h2(pf[o & 3][3].x) * pdh; ah[7] += as_h2(pf[o & 3][3].y) * pdh;
        if (o + 4 <= WMAX) {
            const unsigned char* rp = buf + VOFF + (qid + WMAX - (o + 4)) * RS + s * CS;
            pf[o & 3][0] = *(const uint2*)(rp);
            pf[o & 3][1] = *(const uint2*)(rp + 8);
            pf[o & 3][2] = *(const uint2*)(rp + 16);
            pf[o & 3][3] = *(const uint2*)(rp + 24);
        }
    }

    // ---- pow2 PV: consume ring, prefetch dd+2 ----
    #pragma unroll
    for (int dd = 0; dd < NP2; ++dd) {
        const int d = 64 << dd;
        if (t + QPB - 1 >= d) {
            const float pd = quad_bcast(dd < 4 ? ep0 : ep1, (WMAX + 1 + dd) & 3);
            const h2 pdh = pkrtz(pd, pd);
            #pragma unroll
            for (int u = 0; u < 4; ++u) {
                float4 f = vpf[dd & 1][u];
                ah[u*2+0] += pkrtz(f.x, f.y) * pdh;
                ah[u*2+1] += pkrtz(f.z, f.w) * pdh;
            }
        }
        if (dd + 2 < NP2 && t + QPB - 1 >= (64 << (dd + 2))) {
            const float* vr = vb + (size_t)max(i - (64 << (dd + 2)), 0) * E + ce;
            vpf[dd & 1][0] = *(const float4*)(vr);
            vpf[dd & 1][1] = *(const float4*)(vr + 4);
            vpf[dd & 1][2] = *(const float4*)(vr + 8);
            vpf[dd & 1][3] = *(const float4*)(vr + 12);
        }
    }

    // ---- write this lane's 64B chunk (quad writes contiguous 256B) ----
    float* op = out + base + (size_t)i * E + ce;
    #pragma unroll
    for (int u = 0; u < 4; ++u) {
        float4 o4;
        o4.x = (float)ah[u*2+0].x; o4.y = (float)ah[u*2+0].y;
        o4.z = (float)ah[u*2+1].x; o4.w = (float)ah[u*2+1].y;
        *(float4*)(op + u * 4) = o4;
    }
}

extern "C" void kernel_launch(void* const* d_in, const int* in_sizes, int n_in,
                              void* d_out, int out_size, void* d_ws, size_t ws_size,
                              hipStream_t stream) {
    const float* q = (const float*)d_in[0];
    const float* k = (const float*)d_in[1];
    const float* v = (const float*)d_in[2];
    const int* win = (const int*)d_in[3];
    float* out = (float*)d_out;

    const int n_rows = in_sizes[0] / E;        // B*H*L = 131072
    const int blocks = n_rows / QPB;           // 2048
    logsparse_attn<<<blocks, 256, 0, stream>>>(q, k, v, out, win);
}